// Round 1
// baseline (3818.018 us; speedup 1.0000x reference)
//
#include <hip/hip_runtime.h>
#include <math.h>

#define D_MODEL 512
#define NHEAD 8
#define HD 64
#define BB 8
#define SS 1024
#define QT 8

static __device__ __forceinline__ float wave_max64(float v){
  #pragma unroll
  for (int off = 32; off > 0; off >>= 1) v = fmaxf(v, __shfl_xor(v, off, 64));
  return v;
}
static __device__ __forceinline__ float wave_sum64(float v){
  #pragma unroll
  for (int off = 32; off > 0; off >>= 1) v += __shfl_xor(v, off, 64);
  return v;
}

// 1D conv ('SAME', dilation 1) as implicit GEMM, input [B,S,512] (s-major),
// weight [512][512][KS], output [B,S,512] (s-major).
template<int KS>
__global__ __launch_bounds__(256) void conv_kernel(const float* __restrict__ x,
    const float* __restrict__ W, const float* __restrict__ bias,
    float* __restrict__ out)
{
  constexpr int ST = 16;
  constexpr int NR = ST + KS - 1;
  constexpr int PAD = (KS - 1) / 2;
  __shared__ float xs[NR * D_MODEL];
  const int b  = blockIdx.x / (SS / ST);
  const int s0 = (blockIdx.x % (SS / ST)) * ST;
  const int tid = threadIdx.x;

  for (int idx = tid; idx < NR * D_MODEL; idx += 256) {
    int r = idx / D_MODEL, c = idx - r * D_MODEL;
    int srow = s0 - PAD + r;
    float v = 0.f;
    if (srow >= 0 && srow < SS) v = x[((size_t)b * SS + srow) * D_MODEL + c];
    xs[idx] = v;
  }
  __syncthreads();

  const int o0 = tid, o1 = tid + 256;
  float acc0[ST], acc1[ST];
  {
    float b0 = bias[o0], b1 = bias[o1];
    #pragma unroll
    for (int s = 0; s < ST; s++){ acc0[s] = b0; acc1[s] = b1; }
  }
  const float* w0p = W + (size_t)o0 * D_MODEL * KS;
  const float* w1p = W + (size_t)o1 * D_MODEL * KS;
  for (int i = 0; i < D_MODEL; i++){
    float xr[NR];
    #pragma unroll
    for (int r = 0; r < NR; r++) xr[r] = xs[r * D_MODEL + i];
    #pragma unroll
    for (int k = 0; k < KS; k++){
      float w0 = w0p[i * KS + k];
      float w1 = w1p[i * KS + k];
      #pragma unroll
      for (int s = 0; s < ST; s++){
        acc0[s] = fmaf(xr[s + k], w0, acc0[s]);
        acc1[s] = fmaf(xr[s + k], w1, acc1[s]);
      }
    }
  }
  __syncthreads();
  #pragma unroll
  for (int s = 0; s < ST; s++){
    xs[s * D_MODEL + o0] = acc0[s];
    xs[s * D_MODEL + o1] = acc1[s];
  }
  __syncthreads();
  for (int idx = tid; idx < ST * D_MODEL; idx += 256)
    out[((size_t)b * SS + s0) * D_MODEL + idx] = xs[idx];
}

// Attention: one block per (b, 8 q-rows). Heads sequential; ave_att
// accumulated in LDS (no atomics). K/V staged through padded LDS tiles.
__global__ __launch_bounds__(256) void attn_kernel(
    const float* __restrict__ Q, const float* __restrict__ K,
    const float* __restrict__ V, float* __restrict__ tmp,
    float* __restrict__ ave_out)
{
  extern __shared__ float smem[];
  float* aveL  = smem;                 // QT*SS = 8192
  float* attnL = smem + 8192;          // QT*SS = 8192
  float* Kst   = smem + 16384;         // 256*65 = 16640 (also V stage + reduce scratch)
  float* Qs    = smem + 16384 + 16640; // QT*HD = 512

  const int b  = blockIdx.x / (SS / QT);
  const int s0 = (blockIdx.x % (SS / QT)) * QT;
  const int tid = threadIdx.x;
  const int w = tid >> 6;
  const int l = tid & 63;

  for (int idx = tid; idx < QT * SS; idx += 256) aveL[idx] = 0.f;

  const size_t bQbase = ((size_t)b * SS + s0) * D_MODEL;
  const size_t bKbase = (size_t)b * SS * D_MODEL;

  for (int h = 0; h < NHEAD; h++){
    const int hoff = h * HD;
    // stage Q tile (8 rows x 64)
    for (int idx = tid; idx < QT * HD; idx += 256){
      int q = idx >> 6, d = idx & 63;
      Qs[idx] = Q[bQbase + (size_t)q * D_MODEL + hoff + d];
    }
    // ---- scores: QK^T / 64 into attnL ----
    for (int tb = 0; tb < 4; tb++){
      __syncthreads();  // Kst free (prev phase done), Qs writes done
      for (int idx = tid; idx < 256 * (HD / 4); idx += 256){
        int r = idx >> 4, d4 = (idx & 15) * 4;
        const float4 kv = *reinterpret_cast<const float4*>(
            &K[bKbase + (size_t)(tb * 256 + r) * D_MODEL + hoff + d4]);
        float* dst = &Kst[r * 65 + d4];
        dst[0] = kv.x; dst[1] = kv.y; dst[2] = kv.z; dst[3] = kv.w;
      }
      __syncthreads();
      const int t = tb * 256 + w * 64 + l;
      const float* krow = &Kst[(w * 64 + l) * 65];
      float acc[QT];
      #pragma unroll
      for (int q = 0; q < QT; q++) acc[q] = 0.f;
      for (int d = 0; d < HD; d++){
        float kvv = krow[d];
        #pragma unroll
        for (int q = 0; q < QT; q++) acc[q] = fmaf(Qs[q * 64 + d], kvv, acc[q]);
      }
      #pragma unroll
      for (int q = 0; q < QT; q++) attnL[q * SS + t] = acc[q] * (1.0f / 64.0f);
    }
    __syncthreads();
    // ---- softmax: wave w owns rows 2w, 2w+1 ----
    for (int r = 0; r < 2; r++){
      int q = 2 * w + r;
      float sv[16];
      float m = -1e30f;
      #pragma unroll
      for (int j = 0; j < 16; j++){ sv[j] = attnL[q * SS + l + 64 * j]; m = fmaxf(m, sv[j]); }
      m = wave_max64(m);
      float sum = 0.f;
      #pragma unroll
      for (int j = 0; j < 16; j++){ sv[j] = __expf(sv[j] - m); sum += sv[j]; }
      sum = wave_sum64(sum);
      float inv = 1.0f / sum;
      #pragma unroll
      for (int j = 0; j < 16; j++){
        float a = sv[j] * inv;
        attnL[q * SS + l + 64 * j] = a;
        aveL[q * SS + l + 64 * j] += a;
      }
    }
    // ---- PV: lane owns d=l, wave owns a t-quarter, all 8 q ----
    float pacc[QT];
    #pragma unroll
    for (int q = 0; q < QT; q++) pacc[q] = 0.f;
    for (int tb = 0; tb < 4; tb++){
      __syncthreads();  // all attnL writes + prior Kst reads done
      for (int idx = tid; idx < 256 * (HD / 4); idx += 256){
        int r = idx >> 4, d4 = (idx & 15) * 4;
        const float4 vv = *reinterpret_cast<const float4*>(
            &V[bKbase + (size_t)(tb * 256 + r) * D_MODEL + hoff + d4]);
        float* dst = &Kst[r * 65 + d4];
        dst[0] = vv.x; dst[1] = vv.y; dst[2] = vv.z; dst[3] = vv.w;
      }
      __syncthreads();
      const int tbase = tb * 256 + w * 64;
      for (int tt = 0; tt < 64; tt++){
        float vv = Kst[(w * 64 + tt) * 65 + l];
        #pragma unroll
        for (int q = 0; q < QT; q++)
          pacc[q] = fmaf(attnL[q * SS + tbase + tt], vv, pacc[q]);
      }
    }
    __syncthreads();
    // cross-wave reduce via Kst scratch [4][512]
    #pragma unroll
    for (int q = 0; q < QT; q++) Kst[w * 512 + q * 64 + l] = pacc[q];
    __syncthreads();
    for (int oidx = tid; oidx < 512; oidx += 256){
      float sum = Kst[oidx] + Kst[512 + oidx] + Kst[1024 + oidx] + Kst[1536 + oidx];
      int q = oidx >> 6, d = oidx & 63;
      tmp[bQbase + (size_t)q * D_MODEL + hoff + d] = sum;
    }
    __syncthreads();
  }
  // ---- write ave_att (mean over heads) ----
  for (int idx = tid; idx < QT * SS; idx += 256){
    int q = idx >> 10;
    ave_out[((size_t)b * SS + s0 + q) * SS + (idx & 1023)] = aveL[idx] * 0.125f;
  }
}

// out[b,s,o] = sum_i tmp[b,s,i] * Wo[o,i] + bo[o]
__global__ __launch_bounds__(256) void proj_kernel(const float* __restrict__ tmpIn,
    const float* __restrict__ Wo, const float* __restrict__ bo,
    float* __restrict__ out)
{
  constexpr int ST = 16;
  __shared__ float ts[ST * D_MODEL];
  const int b  = blockIdx.x / (SS / ST);
  const int s0 = (blockIdx.x % (SS / ST)) * ST;
  const int tid = threadIdx.x;
  const size_t base = ((size_t)b * SS + s0) * D_MODEL;
  for (int idx = tid; idx < ST * D_MODEL; idx += 256) ts[idx] = tmpIn[base + idx];
  __syncthreads();
  const int o0 = tid, o1 = tid + 256;
  float acc0[ST], acc1[ST];
  {
    float b0 = bo[o0], b1 = bo[o1];
    #pragma unroll
    for (int s = 0; s < ST; s++){ acc0[s] = b0; acc1[s] = b1; }
  }
  const float* w0 = Wo + (size_t)o0 * D_MODEL;
  const float* w1 = Wo + (size_t)o1 * D_MODEL;
  for (int i = 0; i < D_MODEL; i++){
    float a = w0[i], c = w1[i];
    #pragma unroll
    for (int s = 0; s < ST; s++){
      acc0[s] = fmaf(ts[s * D_MODEL + i], a, acc0[s]);
      acc1[s] = fmaf(ts[s * D_MODEL + i], c, acc1[s]);
    }
  }
  __syncthreads();
  #pragma unroll
  for (int s = 0; s < ST; s++){ ts[s * D_MODEL + o0] = acc0[s]; ts[s * D_MODEL + o1] = acc1[s]; }
  __syncthreads();
  for (int idx = tid; idx < ST * D_MODEL; idx += 256) out[base + idx] = ts[idx];
}

extern "C" void kernel_launch(void* const* d_in, const int* in_sizes, int n_in,
                              void* d_out, int out_size, void* d_ws, size_t ws_size,
                              hipStream_t stream)
{
  const float* query = (const float*)d_in[0];
  const float* key_t = (const float*)d_in[1];
  const float* value = (const float*)d_in[2];
  const float* Wq = (const float*)d_in[3];
  const float* bq = (const float*)d_in[4];
  const float* Wk = (const float*)d_in[5];
  const float* bk = (const float*)d_in[6];
  const float* Wv = (const float*)d_in[7];
  const float* bv = (const float*)d_in[8];
  const float* Wo = (const float*)d_in[9];
  const float* bo = (const float*)d_in[10];

  float* out = (float*)d_out;                       // [B,S,512] = 4194304
  float* ave = out + (size_t)BB * SS * D_MODEL;     // [B,S,S]   = 8388608

  float* ws = (float*)d_ws;
  const size_t BSD = (size_t)BB * SS * D_MODEL;
  float* Qw = ws;            // [B,S,512]
  float* Kw = ws + BSD;      // [B,S,512]
  float* Vw = ws + 2 * BSD;  // [B,S,512]
  float* Tw = ws + 3 * BSD;  // [B,S,512] attention output pre-projection

  const int convGrid = BB * (SS / 16);  // 512
  hipLaunchKernelGGL((conv_kernel<3>), dim3(convGrid), dim3(256), 0, stream, query, Wq, bq, Qw);
  hipLaunchKernelGGL((conv_kernel<3>), dim3(convGrid), dim3(256), 0, stream, key_t, Wk, bk, Kw);
  hipLaunchKernelGGL((conv_kernel<1>), dim3(convGrid), dim3(256), 0, stream, value, Wv, bv, Vw);

  const size_t smem = (size_t)(8192 + 8192 + 256 * 65 + 512) * sizeof(float); // 134144 B
  hipFuncSetAttribute((const void*)attn_kernel,
                      hipFuncAttributeMaxDynamicSharedMemorySize, (int)smem);
  hipLaunchKernelGGL(attn_kernel, dim3(BB * (SS / QT)), dim3(256), smem, stream,
                     Qw, Kw, Vw, Tw, ave);

  hipLaunchKernelGGL(proj_kernel, dim3(convGrid), dim3(256), 0, stream, Tw, Wo, bo, out);
}

// Round 2
// 664.492 us; speedup vs baseline: 5.7458x; 5.7458x over previous
//
#include <hip/hip_runtime.h>
#include <hip/hip_bf16.h>
#include <math.h>

#define BB 8
#define SS 1024
#define DM 512
#define NH 8
#define HD 64

typedef __attribute__((ext_vector_type(8))) short bf16x8;
typedef __attribute__((ext_vector_type(4))) float f32x4;
typedef __hip_bfloat16 bf16;

static __device__ __forceinline__ short f2bs(float f){
  return __builtin_bit_cast(short, __float2bfloat16(f));
}

static __device__ __forceinline__ float wave_max64(float v){
#pragma unroll
  for (int off = 32; off > 0; off >>= 1) v = fmaxf(v, __shfl_xor(v, off, 64));
  return v;
}
static __device__ __forceinline__ float wave_sum64(float v){
#pragma unroll
  for (int off = 32; off > 0; off >>= 1) v += __shfl_xor(v, off, 64);
  return v;
}

// Pack W[o][i][k] f32 -> Wb[k][o][i] bf16 (B-operand wants i contiguous at fixed o).
__global__ __launch_bounds__(256) void pack_w(
    const float* __restrict__ Wq, const float* __restrict__ Wk,
    const float* __restrict__ Wv, const float* __restrict__ Wo,
    bf16* __restrict__ Wqb, bf16* __restrict__ Wkb,
    bf16* __restrict__ Wvb, bf16* __restrict__ Wob)
{
  const int idx = blockIdx.x * 256 + threadIdx.x;   // o*512 + i, 262144 total
#pragma unroll
  for (int k = 0; k < 3; k++){
    Wqb[k * 262144 + idx] = __float2bfloat16(Wq[idx * 3 + k]);
    Wkb[k * 262144 + idx] = __float2bfloat16(Wk[idx * 3 + k]);
  }
  Wvb[idx] = __float2bfloat16(Wv[idx]);
  Wob[idx] = __float2bfloat16(Wo[idx]);
}

// Conv-as-GEMM: out[b,s,o] = sum_{k,i} x[b, s+k-PAD, i] * Wb[k][o][i] + bias[o]
// Tile 32s x 512o per block, 4 waves each own 128 o. A from LDS, B from global.
// TROUT: store transposed out[b][o][s] (for V).
template<int KS, bool IN_BF16, bool OUT_F32, bool TROUT>
__global__ __launch_bounds__(256) void gemm_k(const void* __restrict__ xin,
    const bf16* __restrict__ Wb, const float* __restrict__ bias, void* __restrict__ outv)
{
  constexpr int ST = 32;
  constexpr int PAD = (KS - 1) / 2;
  constexpr int NR = ST + KS - 1;
  constexpr int LDX = DM + 8;                       // bf16 elems, +8 breaks bank aliasing
  constexpr int SMB_A = NR * LDX * 2;
  constexpr int SMB_B = 32 * 257 * 4;
  constexpr int SMB = (SMB_A > SMB_B) ? SMB_A : SMB_B;
  __shared__ char smem[SMB];
  bf16*  xs = (bf16*)smem;
  float* es = (float*)smem;

  const int b   = blockIdx.x / (SS / ST);
  const int s0  = (blockIdx.x % (SS / ST)) * ST;
  const int tid = threadIdx.x;
  const int w = tid >> 6, l = tid & 63;
  const int lr = l & 15, lg = l >> 4;
  const int o0 = w * 128;

  // ---- stage x tile (rows s0-PAD .. s0+ST-1+PAD) as bf16 ----
  if (IN_BF16){
    const bf16* x = (const bf16*)xin;
    for (int idx = tid * 4; idx < NR * DM; idx += 1024){
      int r = idx >> 9, c = idx & 511;
      int srow = s0 - PAD + r;
      ushort4 v; v.x = v.y = v.z = v.w = 0;
      if (srow >= 0 && srow < SS)
        v = *reinterpret_cast<const ushort4*>(&x[((size_t)b * SS + srow) * DM + c]);
      *reinterpret_cast<ushort4*>(&xs[r * LDX + c]) = v;
    }
  } else {
    const float* x = (const float*)xin;
    for (int idx = tid * 4; idx < NR * DM; idx += 1024){
      int r = idx >> 9, c = idx & 511;
      int srow = s0 - PAD + r;
      float4 v = make_float4(0.f, 0.f, 0.f, 0.f);
      if (srow >= 0 && srow < SS)
        v = *reinterpret_cast<const float4*>(&x[((size_t)b * SS + srow) * DM + c]);
      ushort4 u;
      u.x = (unsigned short)f2bs(v.x); u.y = (unsigned short)f2bs(v.y);
      u.z = (unsigned short)f2bs(v.z); u.w = (unsigned short)f2bs(v.w);
      *reinterpret_cast<ushort4*>(&xs[r * LDX + c]) = u;
    }
  }

  float bs[8];
#pragma unroll
  for (int of = 0; of < 8; of++) bs[of] = bias[o0 + of * 16 + lr];

  __syncthreads();

  f32x4 acc[2][8];
#pragma unroll
  for (int sf = 0; sf < 2; sf++)
#pragma unroll
    for (int of = 0; of < 8; of++) acc[sf][of] = (f32x4){0.f, 0.f, 0.f, 0.f};

#pragma unroll
  for (int k = 0; k < KS; k++){
    const bf16* wbk = Wb + (size_t)k * DM * DM + (size_t)o0 * DM;
    for (int ic = 0; ic < 16; ic++){
      const int i0 = ic * 32 + lg * 8;
      bf16x8 a0 = *reinterpret_cast<const bf16x8*>(&xs[(lr +      k) * LDX + i0]);
      bf16x8 a1 = *reinterpret_cast<const bf16x8*>(&xs[(lr + 16 + k) * LDX + i0]);
#pragma unroll
      for (int of = 0; of < 8; of++){
        bf16x8 bw = *reinterpret_cast<const bf16x8*>(&wbk[(size_t)(of * 16 + lr) * DM + i0]);
        acc[0][of] = __builtin_amdgcn_mfma_f32_16x16x32_bf16(a0, bw, acc[0][of], 0, 0, 0);
        acc[1][of] = __builtin_amdgcn_mfma_f32_16x16x32_bf16(a1, bw, acc[1][of], 0, 0, 0);
      }
    }
  }

  // ---- epilogue via LDS transpose, two o-halves of 256 ----
  for (int h2 = 0; h2 < 2; h2++){
    __syncthreads();
    if ((w >> 1) == h2){
      const int ob = (w & 1) * 128;
#pragma unroll
      for (int sf = 0; sf < 2; sf++)
#pragma unroll
        for (int of = 0; of < 8; of++)
#pragma unroll
          for (int r = 0; r < 4; r++)
            es[(sf * 16 + lg * 4 + r) * 257 + ob + of * 16 + lr] = acc[sf][of][r] + bs[of];
    }
    __syncthreads();
    if (!TROUT){
      for (int it = 0; it < 8; it++){
        int t = tid + it * 256;
        int s = t >> 6, c4 = (t & 63) * 4;
        const float* ep = &es[s * 257 + c4];
        if (OUT_F32){
          float* out = (float*)outv;
          float4 v = make_float4(ep[0], ep[1], ep[2], ep[3]);
          *reinterpret_cast<float4*>(&out[((size_t)b * SS + s0 + s) * DM + h2 * 256 + c4]) = v;
        } else {
          bf16* out = (bf16*)outv;
          ushort4 u;
          u.x = (unsigned short)f2bs(ep[0]); u.y = (unsigned short)f2bs(ep[1]);
          u.z = (unsigned short)f2bs(ep[2]); u.w = (unsigned short)f2bs(ep[3]);
          *reinterpret_cast<ushort4*>(&out[((size_t)b * SS + s0 + s) * DM + h2 * 256 + c4]) = u;
        }
      }
    } else {
      bf16* out = (bf16*)outv;   // [B][DM][SS]
      for (int pass = 0; pass < 8; pass++){
        int oc = pass * 32 + (tid >> 3);
        int s4 = (tid & 7) * 4;
        ushort4 u;
        u.x = (unsigned short)f2bs(es[(s4 + 0) * 257 + oc]);
        u.y = (unsigned short)f2bs(es[(s4 + 1) * 257 + oc]);
        u.z = (unsigned short)f2bs(es[(s4 + 2) * 257 + oc]);
        u.w = (unsigned short)f2bs(es[(s4 + 3) * 257 + oc]);
        int o = h2 * 256 + oc;
        *reinterpret_cast<ushort4*>(&out[((size_t)b * DM + o) * SS + s0 + s4]) = u;
      }
    }
  }
}

// Attention: block = (b, 16 q-rows), 4 waves; heads sequential; MFMA QK^T and PV;
// scores + ave in LDS f32 (stride 1028 => 2-way banks max).
#define LDS_SC 1028
__global__ __launch_bounds__(256) void attn2(const bf16* __restrict__ Q,
    const bf16* __restrict__ K, const bf16* __restrict__ Vt,
    bf16* __restrict__ Tw, float* __restrict__ ave)
{
  extern __shared__ float smem[];
  float* scoresL = smem;                 // 16*1028
  float* aveL    = smem + 16 * LDS_SC;   // 16*1028

  const int b   = blockIdx.x >> 6;
  const int s0  = (blockIdx.x & 63) * 16;
  const int tid = threadIdx.x;
  const int w = tid >> 6, l = tid & 63;
  const int lr = l & 15, lg = l >> 4;

  for (int idx = tid; idx < 16 * LDS_SC; idx += 256) aveL[idx] = 0.f;

  const size_t xbase = (size_t)b * SS * DM;   // Q/K/Tw
  const size_t vbase = (size_t)b * DM * SS;   // Vt

  for (int h = 0; h < NH; h++){
    const int hoff = h * HD;
    // Q A-fragments (row = q = lr, k = d)
    bf16x8 qa[2];
#pragma unroll
    for (int kk = 0; kk < 2; kk++)
      qa[kk] = *reinterpret_cast<const bf16x8*>(
          &Q[xbase + (size_t)(s0 + lr) * DM + hoff + kk * 32 + lg * 8]);

    // ---- scores = QK^T / 64 : wave w covers t in [w*256, w*256+256) ----
    for (int tf = 0; tf < 16; tf++){
      const int t0 = w * 256 + tf * 16;
      f32x4 c = (f32x4){0.f, 0.f, 0.f, 0.f};
#pragma unroll
      for (int kk = 0; kk < 2; kk++){
        bf16x8 kb = *reinterpret_cast<const bf16x8*>(
            &K[xbase + (size_t)(t0 + lr) * DM + hoff + kk * 32 + lg * 8]);
        c = __builtin_amdgcn_mfma_f32_16x16x32_bf16(qa[kk], kb, c, 0, 0, 0);
      }
#pragma unroll
      for (int r = 0; r < 4; r++)
        scoresL[(lg * 4 + r) * LDS_SC + t0 + lr] = c[r] * (1.f / 64.f);
    }
    __syncthreads();

    // ---- softmax: wave w owns rows 4w..4w+3, full row in 16 regs/lane ----
    for (int rr = 0; rr < 4; rr++){
      const int q = w * 4 + rr;
      float sv[16];
      float m = -1e30f;
#pragma unroll
      for (int j = 0; j < 16; j++){
        sv[j] = scoresL[q * LDS_SC + l + 64 * j];
        m = fmaxf(m, sv[j]);
      }
      m = wave_max64(m);
      float sum = 0.f;
#pragma unroll
      for (int j = 0; j < 16; j++){ sv[j] = __expf(sv[j] - m); sum += sv[j]; }
      sum = wave_sum64(sum);
      const float inv = 1.f / sum;
#pragma unroll
      for (int j = 0; j < 16; j++){
        const float p = sv[j] * inv;
        scoresL[q * LDS_SC + l + 64 * j] = p;
        aveL[q * LDS_SC + l + 64 * j] += p;
      }
    }
    __syncthreads();

    // ---- PV: wave w accumulates its t-quarter; A = p (LDS->bf16), B = Vt ----
    f32x4 pacc[4];
#pragma unroll
    for (int df = 0; df < 4; df++) pacc[df] = (f32x4){0.f, 0.f, 0.f, 0.f};
    for (int ks8 = 0; ks8 < 8; ks8++){
      const int t0 = w * 256 + ks8 * 32;
      const float* pr = &scoresL[(size_t)lr * LDS_SC + t0 + lg * 8];
      float4 p0 = *reinterpret_cast<const float4*>(pr);
      float4 p1 = *reinterpret_cast<const float4*>(pr + 4);
      bf16x8 pa;
      pa[0] = f2bs(p0.x); pa[1] = f2bs(p0.y); pa[2] = f2bs(p0.z); pa[3] = f2bs(p0.w);
      pa[4] = f2bs(p1.x); pa[5] = f2bs(p1.y); pa[6] = f2bs(p1.z); pa[7] = f2bs(p1.w);
#pragma unroll
      for (int df = 0; df < 4; df++){
        bf16x8 vb = *reinterpret_cast<const bf16x8*>(
            &Vt[vbase + (size_t)(hoff + df * 16 + lr) * SS + t0 + lg * 8]);
        pacc[df] = __builtin_amdgcn_mfma_f32_16x16x32_bf16(pa, vb, pacc[df], 0, 0, 0);
      }
    }
    __syncthreads();   // everyone done reading scoresL -> reuse as reduce scratch

    // scratch[w][q][d] at w*1040 + q*65 + d (65 stride: conflict-free)
#pragma unroll
    for (int df = 0; df < 4; df++)
#pragma unroll
      for (int r = 0; r < 4; r++)
        scoresL[w * 1040 + (lg * 4 + r) * 65 + df * 16 + lr] = pacc[df][r];
    __syncthreads();
    for (int idx = tid; idx < 1024; idx += 256){
      const int q = idx >> 6, d = idx & 63;
      float s = scoresL[q * 65 + d] + scoresL[1040 + q * 65 + d]
              + scoresL[2080 + q * 65 + d] + scoresL[3120 + q * 65 + d];
      Tw[xbase + (size_t)(s0 + q) * DM + hoff + d] = __float2bfloat16(s);
    }
    __syncthreads();
  }

  // ---- ave_att = mean over heads ----
  for (int idx = tid; idx < 16 * SS; idx += 256){
    const int q = idx >> 10, t = idx & 1023;
    ave[((size_t)b * SS + s0 + q) * SS + t] = aveL[q * LDS_SC + t] * 0.125f;
  }
}

extern "C" void kernel_launch(void* const* d_in, const int* in_sizes, int n_in,
                              void* d_out, int out_size, void* d_ws, size_t ws_size,
                              hipStream_t stream)
{
  const float* query = (const float*)d_in[0];
  const float* key_t = (const float*)d_in[1];
  const float* value = (const float*)d_in[2];
  const float* Wq = (const float*)d_in[3];
  const float* bq = (const float*)d_in[4];
  const float* Wk = (const float*)d_in[5];
  const float* bk = (const float*)d_in[6];
  const float* Wv = (const float*)d_in[7];
  const float* bv = (const float*)d_in[8];
  const float* Wo = (const float*)d_in[9];
  const float* bo = (const float*)d_in[10];

  float* out = (float*)d_out;                        // [B,S,512]
  float* ave = out + (size_t)BB * SS * DM;           // [B,S,S]

  char* wsb = (char*)d_ws;
  bf16* Qw  = (bf16*)(wsb);                          // 8 MB  [B,S,512]
  bf16* Kw  = (bf16*)(wsb + 8388608);                // 8 MB  [B,S,512]
  bf16* Vt  = (bf16*)(wsb + 16777216);               // 8 MB  [B,512,S]
  bf16* Tw  = (bf16*)(wsb + 25165824);               // 8 MB  [B,S,512]
  bf16* Wqb = (bf16*)(wsb + 33554432);               // 1.5 MB [3][512][512]
  bf16* Wkb = (bf16*)(wsb + 35127296);               // 1.5 MB
  bf16* Wvb = (bf16*)(wsb + 36700160);               // 0.5 MB [512][512]
  bf16* Wob = (bf16*)(wsb + 37224448);               // 0.5 MB

  hipLaunchKernelGGL(pack_w, dim3(1024), dim3(256), 0, stream,
                     Wq, Wk, Wv, Wo, Wqb, Wkb, Wvb, Wob);

  const int g = BB * (SS / 32);  // 256 blocks
  hipLaunchKernelGGL((gemm_k<3, false, false, false>), dim3(g), dim3(256), 0, stream,
                     (const void*)query, Wqb, bq, (void*)Qw);
  hipLaunchKernelGGL((gemm_k<3, false, false, false>), dim3(g), dim3(256), 0, stream,
                     (const void*)key_t, Wkb, bk, (void*)Kw);
  hipLaunchKernelGGL((gemm_k<1, false, false, true>), dim3(g), dim3(256), 0, stream,
                     (const void*)value, Wvb, bv, (void*)Vt);

  const size_t asmem = (size_t)2 * 16 * LDS_SC * sizeof(float);  // 131584 B
  hipFuncSetAttribute((const void*)attn2,
                      hipFuncAttributeMaxDynamicSharedMemorySize, (int)asmem);
  hipLaunchKernelGGL(attn2, dim3(BB * 64), dim3(256), asmem, stream,
                     Qw, Kw, Vt, Tw, ave);

  hipLaunchKernelGGL((gemm_k<1, true, true, false>), dim3(g), dim3(256), 0, stream,
                     (const void*)Tw, Wob, bo, (void*)out);
}

// Round 3
// 534.275 us; speedup vs baseline: 7.1462x; 1.2437x over previous
//
#include <hip/hip_runtime.h>
#include <hip/hip_bf16.h>

#define BB 8
#define SS 1024
#define DM 512
#define NH 8
#define HD 64

typedef __attribute__((ext_vector_type(8))) short bf16x8;
typedef __attribute__((ext_vector_type(4))) float f32x4;
typedef __hip_bfloat16 bf16;

static __device__ __forceinline__ unsigned short f2bs(float f){
  return (unsigned short)__builtin_bit_cast(short, __float2bfloat16(f));
}

// Pack W[o][i][k] f32 -> Wb[k][o][i] bf16.
__global__ __launch_bounds__(256) void pack_w(
    const float* __restrict__ Wq, const float* __restrict__ Wk,
    const float* __restrict__ Wv, const float* __restrict__ Wo,
    bf16* __restrict__ Wqb, bf16* __restrict__ Wkb,
    bf16* __restrict__ Wvb, bf16* __restrict__ Wob)
{
  const int idx = blockIdx.x * 256 + threadIdx.x;   // o*512 + i
#pragma unroll
  for (int k = 0; k < 3; k++){
    Wqb[k * 262144 + idx] = __float2bfloat16(Wq[idx * 3 + k]);
    Wkb[k * 262144 + idx] = __float2bfloat16(Wk[idx * 3 + k]);
  }
  Wvb[idx] = __float2bfloat16(Wv[idx]);
  Wob[idx] = __float2bfloat16(Wo[idx]);
}

// Conv-as-GEMM, 16s x 256o tile per block (grid 1024), XOR-swizzled LDS A-tile.
// out[b,s,o] = sum_{k,i} x[b,s+k-PAD,i] * Wb[k][o][i] + bias[o]
template<int KS, bool IN_BF16, bool OUT_F32, bool TROUT>
__global__ __launch_bounds__(256) void gemm2(const void* __restrict__ xin,
    const bf16* __restrict__ Wb, const float* __restrict__ bias, void* __restrict__ outv)
{
  constexpr int ST = 16;
  constexpr int PAD = (KS - 1) / 2;
  constexpr int NR = ST + KS - 1;
  constexpr int SMB_A = NR * 1024;          // [NR][512] bf16, swizzled rows
  constexpr int SMB_B = 16 * 260 * 4;       // epilogue f32 [16][260]
  constexpr int SMB = (SMB_A > SMB_B) ? SMB_A : SMB_B;
  __shared__ char smem[SMB];
  char*  xs = smem;
  float* es = (float*)smem;

  const int oh = blockIdx.x & 1;
  const int st = (blockIdx.x >> 1) & 63;
  const int b  = blockIdx.x >> 7;
  const int s0 = st * ST;
  const int tid = threadIdx.x;
  const int w = tid >> 6, l = tid & 63;
  const int lr = l & 15, lg = l >> 4;
  const int o0 = oh * 256 + w * 64;

  // ---- stage x tile as bf16, XOR-swizzle ((r&7)<<4) on row byte offset ----
  for (int idx = tid * 4; idx < NR * DM; idx += 1024){
    const int r = idx >> 9, c = idx & 511;
    const int srow = s0 - PAD + r;
    const int byte = r * 1024 + ((c * 2) ^ ((r & 7) << 4));
    if (IN_BF16){
      ushort4 v = {0, 0, 0, 0};
      if (0 <= srow && srow < SS)
        v = *reinterpret_cast<const ushort4*>((const bf16*)xin + ((size_t)b * SS + srow) * DM + c);
      *reinterpret_cast<ushort4*>(xs + byte) = v;
    } else {
      float4 v = make_float4(0.f, 0.f, 0.f, 0.f);
      if (0 <= srow && srow < SS)
        v = *reinterpret_cast<const float4*>((const float*)xin + ((size_t)b * SS + srow) * DM + c);
      ushort4 u; u.x = f2bs(v.x); u.y = f2bs(v.y); u.z = f2bs(v.z); u.w = f2bs(v.w);
      *reinterpret_cast<ushort4*>(xs + byte) = u;
    }
  }

  float bs[4];
#pragma unroll
  for (int of = 0; of < 4; of++) bs[of] = bias[o0 + of * 16 + lr];

  __syncthreads();

  f32x4 acc[4];
#pragma unroll
  for (int of = 0; of < 4; of++) acc[of] = (f32x4){0.f, 0.f, 0.f, 0.f};

#pragma unroll
  for (int k = 0; k < KS; k++){
    const bf16* wbk = Wb + (size_t)k * DM * DM;
    const int row = lr + k;
    const int rswz = (row & 7) << 4;
    for (int ic = 0; ic < 16; ic++){
      bf16x8 a = *reinterpret_cast<const bf16x8*>(
          xs + row * 1024 + (((ic * 32 + lg * 8) * 2) ^ rswz));
#pragma unroll
      for (int of = 0; of < 4; of++){
        bf16x8 bw = *reinterpret_cast<const bf16x8*>(
            wbk + (size_t)(o0 + of * 16 + lr) * DM + ic * 32 + lg * 8);
        acc[of] = __builtin_amdgcn_mfma_f32_16x16x32_bf16(a, bw, acc[of], 0, 0, 0);
      }
    }
  }

  __syncthreads();
#pragma unroll
  for (int of = 0; of < 4; of++)
#pragma unroll
    for (int r = 0; r < 4; r++)
      es[(lg * 4 + r) * 260 + w * 64 + of * 16 + lr] = acc[of][r] + bs[of];
  __syncthreads();

  if (!TROUT){
#pragma unroll
    for (int it = 0; it < 4; it++){
      const int t = tid + it * 256;
      const int s = t >> 6, c4 = (t & 63) * 4;
      const float* ep = &es[s * 260 + c4];
      if (OUT_F32){
        float4 v = make_float4(ep[0], ep[1], ep[2], ep[3]);
        *reinterpret_cast<float4*>((float*)outv + ((size_t)b * SS + s0 + s) * DM + oh * 256 + c4) = v;
      } else {
        ushort4 u; u.x = f2bs(ep[0]); u.y = f2bs(ep[1]); u.z = f2bs(ep[2]); u.w = f2bs(ep[3]);
        *reinterpret_cast<ushort4*>((bf16*)outv + ((size_t)b * SS + s0 + s) * DM + oh * 256 + c4) = u;
      }
    }
  } else {
    // Vt[b][o][s]: each thread owns one o-column, 16 s values
    const int o = oh * 256 + tid;
    uint us[8];
#pragma unroll
    for (int j = 0; j < 8; j++){
      const float lo = es[(2 * j) * 260 + tid];
      const float hi = es[(2 * j + 1) * 260 + tid];
      us[j] = (uint)f2bs(lo) | ((uint)f2bs(hi) << 16);
    }
    uint4* dst = reinterpret_cast<uint4*>((bf16*)outv + ((size_t)b * DM + o) * SS + s0);
    dst[0] = make_uint4(us[0], us[1], us[2], us[3]);
    dst[1] = make_uint4(us[4], us[5], us[6], us[7]);
  }
}

// Attention: block = (b, head, 16 q-rows); swapped QK^T; P -> swizzled LDS + global Pbuf.
template<int HG>
__global__ __launch_bounds__(256) void attn3(const bf16* __restrict__ Q,
    const bf16* __restrict__ K, const bf16* __restrict__ Vt,
    bf16* __restrict__ Tw, bf16* __restrict__ Pbuf, int h0)
{
  __shared__ char smem[33280];
  char*  plds = smem;                        // [16 q][1024 t] bf16, XOR-swizzled
  float* red  = (float*)smem;                // PV reduce scratch overlay
  float* mxL  = (float*)(smem + 32768);      // [4][16]
  float* smL  = (float*)(smem + 33024);      // [4][16]

  const int qt   = blockIdx.x & 63;
  const int rest = blockIdx.x >> 6;
  const int hl   = rest & (HG - 1);
  const int b    = rest / HG;
  const int h    = h0 + hl;
  const int s0   = qt * 16;
  const int tid  = threadIdx.x;
  const int w = tid >> 6, l = tid & 63;
  const int lr = l & 15, lg = l >> 4;
  const int hoff = h * HD;
  const size_t xb = (size_t)b * SS * DM;

  // Q as B-operand (col = q = lr)
  bf16x8 qb0 = *reinterpret_cast<const bf16x8*>(&Q[xb + (size_t)(s0 + lr) * DM + hoff + lg * 8]);
  bf16x8 qb1 = *reinterpret_cast<const bf16x8*>(&Q[xb + (size_t)(s0 + lr) * DM + hoff + 32 + lg * 8]);

  // ---- scores^T: C[t][q], wave w owns t-quarter [w*256, w*256+256) ----
  f32x4 sc[16];
#pragma unroll
  for (int tf = 0; tf < 16; tf++){
    const int t0 = w * 256 + tf * 16;
    bf16x8 ka0 = *reinterpret_cast<const bf16x8*>(&K[xb + (size_t)(t0 + lr) * DM + hoff + lg * 8]);
    bf16x8 ka1 = *reinterpret_cast<const bf16x8*>(&K[xb + (size_t)(t0 + lr) * DM + hoff + 32 + lg * 8]);
    f32x4 c = (f32x4){0.f, 0.f, 0.f, 0.f};
    c = __builtin_amdgcn_mfma_f32_16x16x32_bf16(ka0, qb0, c, 0, 0, 0);
    c = __builtin_amdgcn_mfma_f32_16x16x32_bf16(ka1, qb1, c, 0, 0, 0);
#pragma unroll
    for (int r = 0; r < 4; r++) sc[tf][r] = c[r] * (1.f / 64.f);
  }

  // ---- softmax over t (lane owns q = lr) ----
  float m = -1e30f;
#pragma unroll
  for (int tf = 0; tf < 16; tf++)
#pragma unroll
    for (int r = 0; r < 4; r++) m = fmaxf(m, sc[tf][r]);
  m = fmaxf(m, __shfl_xor(m, 16, 64));
  m = fmaxf(m, __shfl_xor(m, 32, 64));
  if (l < 16) mxL[w * 16 + l] = m;
  __syncthreads();
  m = fmaxf(fmaxf(mxL[lr], mxL[16 + lr]), fmaxf(mxL[32 + lr], mxL[48 + lr]));

  float sum = 0.f;
#pragma unroll
  for (int tf = 0; tf < 16; tf++)
#pragma unroll
    for (int r = 0; r < 4; r++){ sc[tf][r] = __expf(sc[tf][r] - m); sum += sc[tf][r]; }
  sum += __shfl_xor(sum, 16, 64);
  sum += __shfl_xor(sum, 32, 64);
  if (l < 16) smL[w * 16 + l] = sum;
  __syncthreads();
  const float inv = 1.f / (smL[lr] + smL[16 + lr] + smL[32 + lr] + smL[48 + lr]);

  // ---- pack P -> LDS (swizzled) + global Pbuf ----
  const size_t pb = (((size_t)b * HG + hl) * SS + (s0 + lr)) * SS;
  const int swz = (lr & 7) << 4;
#pragma unroll
  for (int tf = 0; tf < 16; tf++){
    const int t = w * 256 + tf * 16 + lg * 4;
    const uint u0 = (uint)f2bs(sc[tf][0] * inv) | ((uint)f2bs(sc[tf][1] * inv) << 16);
    const uint u1 = (uint)f2bs(sc[tf][2] * inv) | ((uint)f2bs(sc[tf][3] * inv) << 16);
    *reinterpret_cast<uint2*>(plds + lr * 2048 + ((2 * t) ^ swz)) = make_uint2(u0, u1);
    *reinterpret_cast<uint2*>((char*)Pbuf + 2 * (pb + t)) = make_uint2(u0, u1);
  }

  // ---- PV: wave w accumulates its t-quarter (reads only its own P region) ----
  const size_t vbase = (size_t)b * DM * SS;
  f32x4 pacc[4];
#pragma unroll
  for (int df = 0; df < 4; df++) pacc[df] = (f32x4){0.f, 0.f, 0.f, 0.f};
#pragma unroll
  for (int ks = 0; ks < 8; ks++){
    bf16x8 pa = *reinterpret_cast<const bf16x8*>(
        plds + lr * 2048 + ((w * 512 + ks * 64 + lg * 16) ^ swz));
#pragma unroll
    for (int df = 0; df < 4; df++){
      bf16x8 vv = *reinterpret_cast<const bf16x8*>(
          &Vt[vbase + (size_t)(hoff + df * 16 + lr) * SS + w * 256 + ks * 32 + lg * 8]);
      pacc[df] = __builtin_amdgcn_mfma_f32_16x16x32_bf16(pa, vv, pacc[df], 0, 0, 0);
    }
  }
  __syncthreads();   // all PV reads done -> reuse plds as reduce scratch
#pragma unroll
  for (int df = 0; df < 4; df++)
#pragma unroll
    for (int r = 0; r < 4; r++)
      red[w * 1040 + (lg * 4 + r) * 65 + df * 16 + lr] = pacc[df][r];
  __syncthreads();
  {
    const int q = tid >> 4, d4 = (tid & 15) * 4;
    float o[4];
#pragma unroll
    for (int j = 0; j < 4; j++)
      o[j] = red[q * 65 + d4 + j] + red[1040 + q * 65 + d4 + j]
           + red[2080 + q * 65 + d4 + j] + red[3120 + q * 65 + d4 + j];
    ushort4 u; u.x = f2bs(o[0]); u.y = f2bs(o[1]); u.z = f2bs(o[2]); u.w = f2bs(o[3]);
    *reinterpret_cast<ushort4*>(&Tw[xb + (size_t)(s0 + q) * DM + hoff + d4]) = u;
  }
}

// ave[b][q][t] (+)= (1/8) * sum_hl Pbuf[b][hl][q][t]
__global__ __launch_bounds__(256) void reduce_p(const bf16* __restrict__ P,
    float* __restrict__ ave, int nh, int first)
{
  const int idx = blockIdx.x * 256 + threadIdx.x;    // 1,048,576 total
  const int b = idx >> 17;
  const int rem = idx & 131071;
  const int q = rem >> 7;
  const int c8 = (rem & 127) * 8;
  float a[8] = {0.f, 0.f, 0.f, 0.f, 0.f, 0.f, 0.f, 0.f};
  for (int hl = 0; hl < nh; hl++){
    const uint4 v = *reinterpret_cast<const uint4*>(
        &P[(((size_t)b * nh + hl) * SS + q) * SS + c8]);
    const uint uu[4] = {v.x, v.y, v.z, v.w};
#pragma unroll
    for (int j = 0; j < 4; j++){
      a[2 * j]     += __uint_as_float(uu[j] << 16);
      a[2 * j + 1] += __uint_as_float(uu[j] & 0xFFFF0000u);
    }
  }
  float* op = &ave[((size_t)b * SS + q) * SS + c8];
  float r[8];
#pragma unroll
  for (int j = 0; j < 8; j++) r[j] = a[j] * 0.125f;
  if (!first){
    const float4 e0 = *reinterpret_cast<const float4*>(op);
    const float4 e1 = *reinterpret_cast<const float4*>(op + 4);
    r[0] += e0.x; r[1] += e0.y; r[2] += e0.z; r[3] += e0.w;
    r[4] += e1.x; r[5] += e1.y; r[6] += e1.z; r[7] += e1.w;
  }
  *reinterpret_cast<float4*>(op)     = make_float4(r[0], r[1], r[2], r[3]);
  *reinterpret_cast<float4*>(op + 4) = make_float4(r[4], r[5], r[6], r[7]);
}

extern "C" void kernel_launch(void* const* d_in, const int* in_sizes, int n_in,
                              void* d_out, int out_size, void* d_ws, size_t ws_size,
                              hipStream_t stream)
{
  const float* query = (const float*)d_in[0];
  const float* key_t = (const float*)d_in[1];
  const float* value = (const float*)d_in[2];
  const float* Wq = (const float*)d_in[3];
  const float* bq = (const float*)d_in[4];
  const float* Wk = (const float*)d_in[5];
  const float* bk = (const float*)d_in[6];
  const float* Wv = (const float*)d_in[7];
  const float* bv = (const float*)d_in[8];
  const float* Wo = (const float*)d_in[9];
  const float* bo = (const float*)d_in[10];

  float* out = (float*)d_out;                        // [B,S,512] f32
  float* ave = out + (size_t)BB * SS * DM;           // [B,S,S] f32

  char* wsb = (char*)d_ws;
  bf16* Qw  = (bf16*)(wsb);                          // 8 MB [B,S,512]
  bf16* Kw  = (bf16*)(wsb + 8388608);                // 8 MB
  bf16* Vt  = (bf16*)(wsb + 16777216);               // 8 MB [B,512,S]
  bf16* Tw  = (bf16*)(wsb + 25165824);               // 8 MB
  bf16* Wqb = (bf16*)(wsb + 33554432);               // [3][512][512]
  bf16* Wkb = (bf16*)(wsb + 35127296);
  bf16* Wvb = (bf16*)(wsb + 36700160);
  bf16* Wob = (bf16*)(wsb + 37224448);
  bf16* Pb  = (bf16*)(wsb + 37748736);               // up to 128 MB

  hipLaunchKernelGGL(pack_w, dim3(1024), dim3(256), 0, stream,
                     Wq, Wk, Wv, Wo, Wqb, Wkb, Wvb, Wob);

  hipLaunchKernelGGL((gemm2<3, false, false, false>), dim3(1024), dim3(256), 0, stream,
                     (const void*)query, Wqb, bq, (void*)Qw);
  hipLaunchKernelGGL((gemm2<3, false, false, false>), dim3(1024), dim3(256), 0, stream,
                     (const void*)key_t, Wkb, bk, (void*)Kw);
  hipLaunchKernelGGL((gemm2<1, false, false, true>), dim3(1024), dim3(256), 0, stream,
                     (const void*)value, Wvb, bv, (void*)Vt);

  const size_t base = 37748736ull;
  int G;
  if      (ws_size >= base + 134217728ull) G = 1;
  else if (ws_size >= base +  67108864ull) G = 2;
  else if (ws_size >= base +  33554432ull) G = 4;
  else                                     G = 8;
  const int HG = NH / G;

  for (int g = 0; g < G; g++){
    const dim3 grid(BB * HG * 64);
    const int h0 = g * HG;
    switch (HG){
      case 8: hipLaunchKernelGGL((attn3<8>), grid, dim3(256), 0, stream, Qw, Kw, Vt, Tw, Pb, h0); break;
      case 4: hipLaunchKernelGGL((attn3<4>), grid, dim3(256), 0, stream, Qw, Kw, Vt, Tw, Pb, h0); break;
      case 2: hipLaunchKernelGGL((attn3<2>), grid, dim3(256), 0, stream, Qw, Kw, Vt, Tw, Pb, h0); break;
      default: hipLaunchKernelGGL((attn3<1>), grid, dim3(256), 0, stream, Qw, Kw, Vt, Tw, Pb, h0); break;
    }
    hipLaunchKernelGGL(reduce_p, dim3(4096), dim3(256), 0, stream, Pb, ave, HG, g == 0 ? 1 : 0);
  }

  hipLaunchKernelGGL((gemm2<1, true, true, false>), dim3(1024), dim3(256), 0, stream,
                     (const void*)Tw, Wob, bo, (void*)out);
}